// Round 1
// baseline (1707.101 us; speedup 1.0000x reference)
//
#include <hip/hip_runtime.h>

// Only the temporal (LSTM) branch of the reference reaches the output:
// h_gcn is dead in the reference forward. We compute, per node:
//   xt_s = x[n, 52+s] * W_tp + b_tp          (rank-1, folded into A0/C0)
//   2-layer LSTM (H=32, T=12, torch gate order i,f,g,o)
//   out[n] = relu(h1 @ W_fc1 + b_fc1) @ W_fc2 + b_fc2
//
// Parallelization: 1 node per thread. Weights are wave-uniform -> scalar
// loads broadcast via SGPR operand of v_fmac_f32. h-state in registers
// (static indices only); c-state / new-h (dynamically j-indexed) live in
// per-thread LDS columns to avoid scratch spills.

#define TSTEPS 12
#define BS 64

__device__ __forceinline__ float fsig(float x) {
    float e = __expf(-x);                      // v_exp path; e in [0, inf)
    return __builtin_amdgcn_rcpf(1.0f + e);    // 1/(1+e), ~1 ulp
}

__device__ __forceinline__ float ftanh(float x) {
    float ax = fabsf(x);
    float e = __expf(-2.0f * ax);              // in (0,1], no overflow
    float r = (1.0f - e) * __builtin_amdgcn_rcpf(1.0f + e);
    return x < 0.0f ? -r : r;
}

// Fold layer-0 input matmul:
//   A0[r] = dot(Wih0[r,:], W_tp)          (scalar per gate row)
//   C0[r] = dot(Wih0[r,:], b_tp) + bih0[r] + bhh0[r]
//   C1[r] = bih1[r] + bhh1[r]
// ws layout: [0:128) A0, [128:256) C0, [256:384) C1
__global__ void precomp_kernel(const float* __restrict__ Wih0,
                               const float* __restrict__ Wtp,
                               const float* __restrict__ btp,
                               const float* __restrict__ bih0,
                               const float* __restrict__ bhh0,
                               const float* __restrict__ bih1,
                               const float* __restrict__ bhh1,
                               float* __restrict__ ws) {
    int r = threadIdx.x;   // 0..127
    if (r < 128) {
        float a = 0.0f, c = 0.0f;
#pragma unroll
        for (int k = 0; k < 16; ++k) {
            float w = Wih0[r * 16 + k];
            a += w * Wtp[k];
            c += w * btp[k];
        }
        ws[r]       = a;
        ws[128 + r] = c + bih0[r] + bhh0[r];
        ws[256 + r] = bih1[r] + bhh1[r];
    }
}

__global__ __launch_bounds__(BS) void lstm_kernel(
    const float* __restrict__ x,
    const float* __restrict__ Whh0,   // [128,32]
    const float* __restrict__ Wih1,   // [128,32]
    const float* __restrict__ Whh1,   // [128,32]
    const float* __restrict__ Wfc1,   // [32,16]
    const float* __restrict__ bfc1,   // [16]
    const float* __restrict__ Wfc2,   // [16]
    const float* __restrict__ bfc2,   // [1]
    const float* __restrict__ pre,    // [384] from precomp
    float* __restrict__ out, int N)
{
    // Per-thread columns: address = j*BS + tid -> consecutive lanes hit
    // consecutive banks (2 lanes/bank for wave64 = free). No cross-thread
    // sharing -> no __syncthreads needed.
    __shared__ float sc0[32 * BS];
    __shared__ float sc1[32 * BS];
    __shared__ float snh[32 * BS];

    const int tid = threadIdx.x;
    const int n = blockIdx.x * BS + tid;
    const int nn = (n < N) ? n : (N > 0 ? N - 1 : 0);
    const float* xr = x + (size_t)nn * 64 + 52;   // last 12 features

    float h0[32], h1[32];
#pragma unroll
    for (int k = 0; k < 32; ++k) { h0[k] = 0.0f; h1[k] = 0.0f; }
#pragma unroll
    for (int j = 0; j < 32; ++j) { sc0[j * BS + tid] = 0.0f; sc1[j * BS + tid] = 0.0f; }

#pragma unroll 1
    for (int t = 0; t < TSTEPS; ++t) {
        const float xval = xr[t];

        // ---------------- layer 0 ----------------
#pragma unroll 1
        for (int j = 0; j < 32; ++j) {
            float gi = pre[128 + j]      + xval * pre[j];
            float gf = pre[128 + 32 + j] + xval * pre[32 + j];
            float gg = pre[128 + 64 + j] + xval * pre[64 + j];
            float go = pre[128 + 96 + j] + xval * pre[96 + j];
            const float* w = Whh0 + j * 32;   // rows j, j+32, j+64, j+96
#pragma unroll
            for (int k = 0; k < 32; ++k) {
                const float hk = h0[k];
                gi += w[k]        * hk;
                gf += w[1024 + k] * hk;
                gg += w[2048 + k] * hk;
                go += w[3072 + k] * hk;
            }
            const float cc = fsig(gf) * sc0[j * BS + tid] + fsig(gi) * ftanh(gg);
            sc0[j * BS + tid] = cc;
            snh[j * BS + tid] = fsig(go) * ftanh(cc);
        }
#pragma unroll
        for (int j = 0; j < 32; ++j) h0[j] = snh[j * BS + tid];

        // ---------------- layer 1 ----------------
#pragma unroll 1
        for (int j = 0; j < 32; ++j) {
            float gi = pre[256 + j];
            float gf = pre[256 + 32 + j];
            float gg = pre[256 + 64 + j];
            float go = pre[256 + 96 + j];
            const float* wi = Wih1 + j * 32;
            const float* wh = Whh1 + j * 32;
#pragma unroll
            for (int k = 0; k < 32; ++k) {
                const float ak = h0[k];
                const float bk = h1[k];
                gi += wi[k]        * ak + wh[k]        * bk;
                gf += wi[1024 + k] * ak + wh[1024 + k] * bk;
                gg += wi[2048 + k] * ak + wh[2048 + k] * bk;
                go += wi[3072 + k] * ak + wh[3072 + k] * bk;
            }
            const float cc = fsig(gf) * sc1[j * BS + tid] + fsig(gi) * ftanh(gg);
            sc1[j * BS + tid] = cc;
            snh[j * BS + tid] = fsig(go) * ftanh(cc);
        }
#pragma unroll
        for (int j = 0; j < 32; ++j) h1[j] = snh[j * BS + tid];
    }

    // epilogue: relu(h1 @ Wfc1 + bfc1) @ Wfc2 + bfc2
    float acc = bfc2[0];
#pragma unroll 1
    for (int m = 0; m < 16; ++m) {
        float a = bfc1[m];
#pragma unroll
        for (int k = 0; k < 32; ++k) a += h1[k] * Wfc1[k * 16 + m];
        acc += fmaxf(a, 0.0f) * Wfc2[m];
    }

    if (n < N) out[n] = acc;
}

extern "C" void kernel_launch(void* const* d_in, const int* in_sizes, int n_in,
                              void* d_out, int out_size, void* d_ws, size_t ws_size,
                              hipStream_t stream) {
    (void)n_in; (void)out_size; (void)ws_size;
    // setup_inputs() order:
    // 0 x, 1 edge_index, 2 W_fp, 3 b_fp, 4 W_g1, 5 b_g1, 6 W_g2, 7 b_g2,
    // 8 W_g3, 9 b_g3, 10 W_tp, 11 b_tp, 12 Wih0, 13 Whh0, 14 bih0, 15 bhh0,
    // 16 Wih1, 17 Whh1, 18 bih1, 19 bhh1, 20 W_fc1, 21 b_fc1, 22 W_fc2, 23 b_fc2
    const float* x    = (const float*)d_in[0];
    const float* Wtp  = (const float*)d_in[10];
    const float* btp  = (const float*)d_in[11];
    const float* Wih0 = (const float*)d_in[12];
    const float* Whh0 = (const float*)d_in[13];
    const float* bih0 = (const float*)d_in[14];
    const float* bhh0 = (const float*)d_in[15];
    const float* Wih1 = (const float*)d_in[16];
    const float* Whh1 = (const float*)d_in[17];
    const float* bih1 = (const float*)d_in[18];
    const float* bhh1 = (const float*)d_in[19];
    const float* Wfc1 = (const float*)d_in[20];
    const float* bfc1 = (const float*)d_in[21];
    const float* Wfc2 = (const float*)d_in[22];
    const float* bfc2 = (const float*)d_in[23];

    float* out = (float*)d_out;
    float* pre = (float*)d_ws;   // 384 floats

    const int N = in_sizes[0] / 64;

    precomp_kernel<<<1, 128, 0, stream>>>(Wih0, Wtp, btp, bih0, bhh0, bih1, bhh1, pre);
    lstm_kernel<<<(N + BS - 1) / BS, BS, 0, stream>>>(
        x, Whh0, Wih1, Whh1, Wfc1, bfc1, Wfc2, bfc2, pre, out, N);
}